// Round 1
// baseline (67.117 us; speedup 1.0000x reference)
//
#include <hip/hip_runtime.h>
#include <hip/hip_bf16.h>

// CP tensorized embedding gather:
// out[t, e] = sum_r U0[a,r]*U1[b,r]*U2[c,r]*V0[d,r]*V1[q,r]
//   idx = x[t];  a = idx/5000; b = (idx/50)%100; c = idx%50
//   e in [0,128); d = e/16; q = e%16
// Never materialize the 500000x128 table. Memory floor = the 105 MB output.

#define RANKK 32
#define EMB 128
#define BATCH 64   // tokens staged per block iteration

__global__ __launch_bounds__(256) void cpemb_kernel(
    const int* __restrict__ x,
    const float* __restrict__ U0, const float* __restrict__ U1,
    const float* __restrict__ U2,
    const float* __restrict__ V0, const float* __restrict__ V1,
    float* __restrict__ out, int ntok)
{
    __shared__ float wsh[BATCH][RANKK];   // 8 KB, stride 32: writes are 2-way
                                          // (free), reads are wave-uniform broadcast
    const int tid  = threadIdx.x;
    const int lane = tid & 63;
    const int wave = tid >> 6;

    // Per-thread slice of B[e][r] = V0[e>>4][r]*V1[e&15][r]; this thread owns
    // e0 = 2*lane, e1 = 2*lane+1 for every token (64 VGPRs).
    const int e0 = 2 * lane, e1 = e0 + 1;
    const int d0 = e0 >> 4, q0 = e0 & 15;
    const int d1 = e1 >> 4, q1 = e1 & 15;
    float B0[RANKK], B1[RANKK];
    #pragma unroll
    for (int r = 0; r < RANKK; ++r) {
        B0[r] = V0[d0 * RANKK + r] * V1[q0 * RANKK + r];
        B1[r] = V0[d1 * RANKK + r] * V1[q1 * RANKK + r];
    }

    for (int base = blockIdx.x * BATCH; base < ntok; base += gridDim.x * BATCH) {
        // ---- phase 1: stage w[t][r] for this batch into LDS ----
        {
            const int r    = tid & 31;   // rank element
            const int tsub = tid >> 5;   // 8 tokens in parallel
            #pragma unroll
            for (int k = 0; k < BATCH / 8; ++k) {
                const int t  = tsub + k * 8;
                const int gt = base + t;
                if (gt < ntok) {
                    const unsigned ui  = (unsigned)x[gt];
                    const unsigned a   = ui / 5000u;
                    const unsigned rem = ui - a * 5000u;
                    const unsigned b   = rem / 50u;
                    const unsigned c   = rem - b * 50u;
                    wsh[t][r] = U0[a * RANKK + r] * U1[b * RANKK + r]
                              * U2[c * RANKK + r];
                }
            }
        }
        __syncthreads();

        // ---- phase 2: one token per wave per step; B in regs, w broadcast ----
        #pragma unroll 1
        for (int t = wave; t < BATCH; t += 4) {
            const int gt = base + t;
            if (gt >= ntok) break;
            const float4* wp = (const float4*)wsh[t];
            float acc0 = 0.f, acc1 = 0.f;
            #pragma unroll
            for (int rr = 0; rr < RANKK / 4; ++rr) {
                const float4 wv = wp[rr];   // ds_read_b128, wave-uniform
                acc0 += wv.x * B0[rr * 4 + 0]; acc1 += wv.x * B1[rr * 4 + 0];
                acc0 += wv.y * B0[rr * 4 + 1]; acc1 += wv.y * B1[rr * 4 + 1];
                acc0 += wv.z * B0[rr * 4 + 2]; acc1 += wv.z * B1[rr * 4 + 2];
                acc0 += wv.w * B0[rr * 4 + 3]; acc1 += wv.w * B1[rr * 4 + 3];
            }
            *(float2*)&out[(size_t)gt * EMB + e0] = make_float2(acc0, acc1);
        }
        __syncthreads();
    }
}

extern "C" void kernel_launch(void* const* d_in, const int* in_sizes, int n_in,
                              void* d_out, int out_size, void* d_ws, size_t ws_size,
                              hipStream_t stream) {
    const int*   x  = (const int*)d_in[0];
    const float* U0 = (const float*)d_in[1];
    const float* U1 = (const float*)d_in[2];
    const float* U2 = (const float*)d_in[3];
    const float* V0 = (const float*)d_in[4];
    const float* V1 = (const float*)d_in[5];
    float* out = (float*)d_out;

    const int ntok = in_sizes[0];                    // 1024*200 = 204800
    const int grid = (ntok + BATCH - 1) / BATCH;     // 3200 blocks

    cpemb_kernel<<<grid, 256, 0, stream>>>(x, U0, U1, U2, V0, V1, out, ntok);
}

// Round 2
// 27.033 us; speedup vs baseline: 2.4828x; 2.4828x over previous
//
#include <hip/hip_runtime.h>
#include <hip/hip_bf16.h>

// CP tensorized embedding gather via MFMA:
// out[t, e] = sum_r w[t,r] * B[r,e]
//   w[t,r] = U0[a,r]*U1[b,r]*U2[c,r], idx=x[t], a=idx/5000, b=(idx/50)%100, c=idx%50
//   B[r,e] = V0[e>>4,r]*V1[e&15,r]
// One v_mfma_f32_16x16x32_bf16 computes a 16-token x 16-e tile (K=32=RANK).
// No LDS, no barriers: U-tables (32 KB) are L1-resident gathers; B-frags are
// loop-invariant registers. Memory floor = the 105 MB f32 output (~17 us).

#define RANKK 32
#define EMB 128
#define WAVES_PER_BLOCK 4

typedef __attribute__((ext_vector_type(8))) short short8v;  // 8 bf16 = 4 VGPRs
typedef __attribute__((ext_vector_type(4))) float f32x4;

__device__ __forceinline__ short f2bf(float f) {
    union { __hip_bfloat16 h; short s; } u;
    u.h = __float2bfloat16(f);   // RNE
    return u.s;
}

__global__ __launch_bounds__(256) void cpemb_mfma(
    const int* __restrict__ x,
    const float* __restrict__ U0, const float* __restrict__ U1,
    const float* __restrict__ U2,
    const float* __restrict__ V0, const float* __restrict__ V1,
    float* __restrict__ out, int ntok)
{
    const int tid  = threadIdx.x;
    const int lane = tid & 63;
    const int gwave  = blockIdx.x * WAVES_PER_BLOCK + (tid >> 6);
    const int nwaves = gridDim.x * WAVES_PER_BLOCK;

    const int t_l = lane & 15;   // A-row lane role == D-col lane role
    const int g   = lane >> 4;   // k-chunk group
    const int rb  = g * 8;       // this lane's rank base (k = rb..rb+7)

    // ---- loop-invariant B-fragments: B[r][e] for e-block eb, col = eb*16+t_l
    // lane's V1 row = t_l (same for every eb); V0 row = eb (lane-uniform).
    float v1r[8];
    {
        const float4* p = (const float4*)(V1 + t_l * RANKK + rb);
        float4 lo = p[0], hi = p[1];
        v1r[0]=lo.x; v1r[1]=lo.y; v1r[2]=lo.z; v1r[3]=lo.w;
        v1r[4]=hi.x; v1r[5]=hi.y; v1r[6]=hi.z; v1r[7]=hi.w;
    }
    short8v bfrag[8];
    #pragma unroll
    for (int eb = 0; eb < 8; ++eb) {
        const float4* p = (const float4*)(V0 + eb * RANKK + rb);
        float4 lo = p[0], hi = p[1];
        float v0r[8] = {lo.x, lo.y, lo.z, lo.w, hi.x, hi.y, hi.z, hi.w};
        #pragma unroll
        for (int i = 0; i < 8; ++i)
            bfrag[eb][i] = f2bf(v0r[i] * v1r[i]);
    }

    const int ngroups = (ntok + 15) >> 4;   // 16 tokens per group
    for (int grp = gwave; grp < ngroups; grp += nwaves) {
        const int t0 = grp << 4;

        // ---- A-fragment: token = t0 + t_l, ranks rb..rb+7 (L1 gathers)
        int tok = t0 + t_l;
        if (tok >= ntok) tok = ntok - 1;           // tail clamp (dup row, masked on store)
        const unsigned ui  = (unsigned)x[tok];
        const unsigned a   = ui / 5000u;
        const unsigned rem = ui - a * 5000u;
        const unsigned b   = rem / 50u;
        const unsigned c   = rem - b * 50u;

        const float4* p0 = (const float4*)(U0 + a * RANKK + rb);
        const float4* p1 = (const float4*)(U1 + b * RANKK + rb);
        const float4* p2 = (const float4*)(U2 + c * RANKK + rb);
        float4 a0 = p0[0], a1 = p0[1];
        float4 b0 = p1[0], b1 = p1[1];
        float4 c0 = p2[0], c1 = p2[1];
        float wv[8];
        wv[0]=a0.x*b0.x*c0.x; wv[1]=a0.y*b0.y*c0.y;
        wv[2]=a0.z*b0.z*c0.z; wv[3]=a0.w*b0.w*c0.w;
        wv[4]=a1.x*b1.x*c1.x; wv[5]=a1.y*b1.y*c1.y;
        wv[6]=a1.z*b1.z*c1.z; wv[7]=a1.w*b1.w*c1.w;
        short8v afrag;
        #pragma unroll
        for (int i = 0; i < 8; ++i) afrag[i] = f2bf(wv[i]);

        // ---- 8 MFMAs (A shared across all e-blocks), then store D
        #pragma unroll
        for (int eb = 0; eb < 8; ++eb) {
            f32x4 acc = {0.f, 0.f, 0.f, 0.f};
            acc = __builtin_amdgcn_mfma_f32_16x16x32_bf16(afrag, bfrag[eb], acc, 0, 0, 0);
            // D: row(token) = t0 + g*4 + j, col(e) = eb*16 + t_l  [m89-verified]
            #pragma unroll
            for (int j = 0; j < 4; ++j) {
                const int trow = t0 + g * 4 + j;
                if (trow < ntok)
                    out[(size_t)trow * EMB + eb * 16 + t_l] = acc[j];
            }
        }
    }
}

extern "C" void kernel_launch(void* const* d_in, const int* in_sizes, int n_in,
                              void* d_out, int out_size, void* d_ws, size_t ws_size,
                              hipStream_t stream) {
    const int*   x  = (const int*)d_in[0];
    const float* U0 = (const float*)d_in[1];
    const float* U1 = (const float*)d_in[2];
    const float* U2 = (const float*)d_in[3];
    const float* V0 = (const float*)d_in[4];
    const float* V1 = (const float*)d_in[5];
    float* out = (float*)d_out;

    const int ntok = in_sizes[0];   // 204800
    const int blocks = 1024;        // 4 blocks/CU, 4096 waves, ~3 groups/wave

    cpemb_mfma<<<blocks, 256, 0, stream>>>(x, U0, U1, U2, V0, V1, out, ntok);
}